// Round 13
// baseline (422.518 us; speedup 1.0000x reference)
//
#include <hip/hip_runtime.h>
#include <math.h>

#define NB 32
#define NC 128
#define NT 4096
#define LTOT 982832   // (4096-1)*240 + 32
#define BT 64

__device__ __forceinline__ float lrelu_(float x) { return x > 0.0f ? x : 0.1f * x; }
// channel-granule XOR swizzle (row-strided b128 reads conflict-free) — env2/sel2 tiles
__device__ __forceinline__ int swz_(int row, int ch) {
    return ((ch & ~3) ^ ((row & 56) >> 1)) | (ch & 3);
}

// ---------- K0: build folded conv weights ----------
// Weff[c][half][oo][k] = pw[o][c] * dw[c][k]   (o = half*32+oo), 24576 floats/path
// Beff[o] = pwb[o] + sum_c pw[o][c]*dwb[c]     (64 floats/path)
__global__ __launch_bounds__(256)
void k_wt2(const float* __restrict__ pw1w, const float* __restrict__ dw1w,
           const float* __restrict__ dw1b, const float* __restrict__ pw1b,
           const float* __restrict__ spww, const float* __restrict__ sdww,
           const float* __restrict__ sdwb, const float* __restrict__ spwb,
           float* __restrict__ weff1, float* __restrict__ beff1,
           float* __restrict__ weff2, float* __restrict__ beff2)
{
    const int e = blockIdx.x * 256 + threadIdx.x;
    if (e < 24576) {
        const int c  = e / 192;
        const int r  = e - c * 192;
        const int hf = r / 96;
        const int rr = r - hf * 96;
        const int oo = rr / 3;
        const int k  = rr - oo * 3;
        const int o  = hf * 32 + oo;
        weff1[e] = pw1w[o * 128 + c] * dw1w[c * 3 + k];
        weff2[e] = spww[o * 128 + c] * sdww[c * 3 + k];
    } else if (e < 24576 + 128) {
        const int i = e - 24576;       // 0..127 : path = i>>6, o = i&63
        const int o = i & 63;
        if (i < 64) {
            float s = pw1b[o];
            for (int c = 0; c < 128; ++c) s = fmaf(pw1w[o * 128 + c], dw1b[c], s);
            beff1[o] = s;
        } else {
            float s = spwb[o];
            for (int c = 0; c < 128; ++c) s = fmaf(spww[o * 128 + c], sdwb[c], s);
            beff2[o] = s;
        }
    }
}

// ---------- K1/K3: folded k3 conv 128->64 + lrelu -> [b][t][64] ----------
// R11 skeleton (acc[32], wave-uniform o-half, SGPR weights, no LDS/barriers).
// Per channel: 3 loads feed 96 FMAs (32 outs x 3 taps) from Weff.
__global__ __launch_bounds__(256, 4)
void k_stage1w(const float* __restrict__ cond,
               const float* __restrict__ weff, const float* __restrict__ beff,
               float* __restrict__ out64)
{
    const int tid  = threadIdx.x;
    const int lane = tid & 63;
    const int wv   = tid >> 6;                      // 0..3
    const int cgrp = wv >> 1;                       // 0..1 : col group
    const int hoff = __builtin_amdgcn_readfirstlane((wv & 1) * 96);   // weight half
    const int so0  = __builtin_amdgcn_readfirstlane((wv & 1) * 32);   // o-half base

    const int col = blockIdx.x * 128 + cgrp * 64 + lane;   // global column b*NT+t
    const int b   = col >> 12;
    const int t   = col & (NT - 1);
    const float* xp = cond + (size_t)b * NC * NT + t;
    const bool gm = (t >= 1);
    const bool gp = (t + 1 < NT);

    float acc[32];
    #pragma unroll
    for (int o = 0; o < 32; ++o) acc[o] = 0.0f;

    const float* wb0 = weff + hoff;

    #pragma unroll 2
    for (int c = 0; c < NC; ++c) {
        const float xm = gm ? xp[-1] : 0.0f;
        const float xc = xp[0];
        const float xq = gp ? xp[1] : 0.0f;
        const float* wr = wb0 + c * 192;            // wave-uniform -> s_load
        #pragma unroll
        for (int og = 0; og < 8; ++og) {
            const float4 wa = *(const float4*)(wr + og * 12);
            const float4 wbv = *(const float4*)(wr + og * 12 + 4);
            const float4 wc2 = *(const float4*)(wr + og * 12 + 8);
            acc[og * 4 + 0] = fmaf(wa.x,  xm, fmaf(wa.y,  xc, fmaf(wa.z,  xq, acc[og * 4 + 0])));
            acc[og * 4 + 1] = fmaf(wa.w,  xm, fmaf(wbv.x, xc, fmaf(wbv.y, xq, acc[og * 4 + 1])));
            acc[og * 4 + 2] = fmaf(wbv.z, xm, fmaf(wbv.w, xc, fmaf(wc2.x, xq, acc[og * 4 + 2])));
            acc[og * 4 + 3] = fmaf(wc2.y, xm, fmaf(wc2.z, xc, fmaf(wc2.w, xq, acc[og * 4 + 3])));
        }
        xp += NT;
    }

    float* op = out64 + (size_t)col * 64 + so0;
    #pragma unroll
    for (int g = 0; g < 8; ++g) {
        const float4 bb = *(const float4*)&beff[so0 + g * 4];
        float4 r;
        r.x = lrelu_(acc[g * 4 + 0] + bb.x);
        r.y = lrelu_(acc[g * 4 + 1] + bb.y);
        r.z = lrelu_(acc[g * 4 + 2] + bb.z);
        r.w = lrelu_(acc[g * 4 + 3] + bb.w);
        *(float4*)(op + g * 4) = r;
    }
}

// ---------- K2: dw2(k3,64ch) -> pw2(64->32)+lrelu -> env(k3,32->1) -> sigmoid ----------
__global__ __launch_bounds__(256)
void k_env2(const float* __restrict__ y1,   // [b][t][64]
            const float* __restrict__ dw2w, const float* __restrict__ dw2b,
            const float* __restrict__ pw2w, const float* __restrict__ pw2b,
            const float* __restrict__ envw, const float* __restrict__ envb,
            float* __restrict__ envout)
{
    __shared__ float Y1T[70 * 68];
    __shared__ float H2T[68 * 68];
    float* Y2T = Y1T;

    const int tid = threadIdx.x;
    const int b   = blockIdx.y;
    const int t0  = blockIdx.x * BT;

    for (int i = tid; i < 70 * 64; i += 256) {
        int j = i >> 6, o = i & 63;
        int t = t0 - 3 + j;
        Y1T[j * 68 + o] = (t >= 0 && t < NT) ? y1[((size_t)b * NT + t) * 64 + o] : 0.0f;
    }
    __syncthreads();

    {
        const int o = tid & 63;
        const int g = tid >> 6;
        const float d0 = dw2w[o * 3 + 0], d1 = dw2w[o * 3 + 1], d2 = dw2w[o * 3 + 2], db = dw2b[o];
        float y[19];
        #pragma unroll
        for (int k = 0; k < 19; ++k) y[k] = Y1T[(g * 17 + k) * 68 + o];
        #pragma unroll
        for (int i = 0; i < 17; ++i) {
            int jj = g * 17 + i;
            H2T[jj * 68 + swz_(jj, o)] = fmaf(d0, y[i], fmaf(d1, y[i + 1], fmaf(d2, y[i + 2], db)));
        }
    }
    __syncthreads();

    {
        const int v  = tid & 63;
        const int wu = __builtin_amdgcn_readfirstlane(threadIdx.x >> 6);
        const float* wbase = pw2w + wu * 8 * 64;
        float acc[8], acc2[8];
        #pragma unroll
        for (int q = 0; q < 8; ++q) { acc[q] = 0.0f; acc2[q] = 0.0f; }
        const int r1 = v + 1;
        const int r2 = (v < 2) ? v + 65 : v + 1;
        const float* h1 = &H2T[r1 * 68]; const int x1 = (r1 & 56) >> 1;
        const float* h2 = &H2T[r2 * 68]; const int x2 = (r2 & 56) >> 1;
        #pragma unroll 2
        for (int cc = 0; cc < 64; cc += 4) {
            const float4 a  = *(const float4*)&h1[cc ^ x1];
            const float4 c2 = *(const float4*)&h2[cc ^ x2];
            #pragma unroll
            for (int q = 0; q < 8; ++q) {
                const float4 wv = *(const float4*)&wbase[q * 64 + cc];
                acc[q]  = fmaf(wv.x, a.x,  fmaf(wv.y, a.y,  fmaf(wv.z, a.z,  fmaf(wv.w, a.w,  acc[q]))));
                acc2[q] = fmaf(wv.x, c2.x, fmaf(wv.y, c2.y, fmaf(wv.z, c2.z, fmaf(wv.w, c2.w, acc2[q]))));
            }
        }
        const int t1 = t0 - 1 + v;
        const bool ok1 = (t1 >= 0 && t1 < NT);
        #pragma unroll
        for (int q = 0; q < 8; ++q) {
            const float bq = pw2b[wu * 8 + q];
            Y2T[v * 37 + wu * 8 + q] = ok1 ? lrelu_(acc[q] + bq) : 0.0f;
        }
        if (v < 2) {
            const int ve = v + 64;
            const int t2 = t0 - 1 + ve;
            const bool ok2 = (t2 >= 0 && t2 < NT);
            #pragma unroll
            for (int q = 0; q < 8; ++q) {
                const float bq = pw2b[wu * 8 + q];
                Y2T[ve * 37 + wu * 8 + q] = ok2 ? lrelu_(acc2[q] + bq) : 0.0f;
            }
        }
    }
    __syncthreads();

    {
        const int j  = tid >> 2;
        const int cp = tid & 3;
        float a = 0.0f;
        #pragma unroll
        for (int d = 0; d < 3; ++d) {
            const float* yr = &Y2T[(j + d) * 37 + cp * 8];
            #pragma unroll
            for (int k = 0; k < 8; ++k)
                a = fmaf(envw[(cp * 8 + k) * 3 + d], yr[k], a);
        }
        a += __shfl_xor(a, 1);
        a += __shfl_xor(a, 2);
        if (cp == 0) {
            const float z = a + envb[0];
            envout[(size_t)b * NT + t0 + j] = 1.0f / (1.0f + expf(-z));
        }
    }
}

// ---------- K4: sel conv (64->16, k3) -> top3 -> softmax ----------
__global__ __launch_bounds__(256)
void k_sel2(const float* __restrict__ ss,   // [b][t][64]
            const float* __restrict__ selw, const float* __restrict__ selb,
            float4* __restrict__ selout)
{
    __shared__ float SST[66 * 68];
    __shared__ float Lg[16 * 64];

    const int tid = threadIdx.x;
    const int b   = blockIdx.y;
    const int t0  = blockIdx.x * BT;

    for (int i = tid; i < 66 * 64; i += 256) {
        int j = i >> 6, o = i & 63;
        int t = t0 - 1 + j;
        SST[j * 68 + swz_(j, o)] = (t >= 0 && t < NT) ? ss[((size_t)b * NT + t) * 64 + o] : 0.0f;
    }
    __syncthreads();

    {
        const int v  = tid & 63;
        const int wu = __builtin_amdgcn_readfirstlane(threadIdx.x >> 6);
        float acc[4] = {0.0f, 0.0f, 0.0f, 0.0f};
        const float* r0 = &SST[(v + 0) * 68]; const int x0 = ((v + 0) & 56) >> 1;
        const float* r1 = &SST[(v + 1) * 68]; const int x1 = ((v + 1) & 56) >> 1;
        const float* r2 = &SST[(v + 2) * 68]; const int x2 = ((v + 2) & 56) >> 1;
        #pragma unroll 2
        for (int cc = 0; cc < 64; cc += 4) {
            const float4 s0 = *(const float4*)&r0[cc ^ x0];
            const float4 s1 = *(const float4*)&r1[cc ^ x1];
            const float4 s2 = *(const float4*)&r2[cc ^ x2];
            #pragma unroll
            for (int q = 0; q < 4; ++q) {
                const float* wr = selw + (size_t)(wu * 4 + q) * 192 + cc * 3;
                const float4 wA = *(const float4*)&wr[0];
                const float4 wB = *(const float4*)&wr[4];
                const float4 wC = *(const float4*)&wr[8];
                acc[q] = fmaf(wA.x, s0.x, acc[q]); acc[q] = fmaf(wA.y, s1.x, acc[q]); acc[q] = fmaf(wA.z, s2.x, acc[q]);
                acc[q] = fmaf(wA.w, s0.y, acc[q]); acc[q] = fmaf(wB.x, s1.y, acc[q]); acc[q] = fmaf(wB.y, s2.y, acc[q]);
                acc[q] = fmaf(wB.z, s0.z, acc[q]); acc[q] = fmaf(wB.w, s1.z, acc[q]); acc[q] = fmaf(wC.x, s2.z, acc[q]);
                acc[q] = fmaf(wC.y, s0.w, acc[q]); acc[q] = fmaf(wC.z, s1.w, acc[q]); acc[q] = fmaf(wC.w, s2.w, acc[q]);
            }
        }
        #pragma unroll
        for (int q = 0; q < 4; ++q)
            Lg[(wu * 4 + q) * 64 + v] = acc[q] + selb[wu * 4 + q];
    }
    __syncthreads();

    if (tid < 64) {
        const int jt = tid;
        float v[16];
        #pragma unroll
        for (int a = 0; a < 16; ++a) v[a] = Lg[a * 64 + jt];
        int i0 = 0; float m0 = v[0];
        #pragma unroll
        for (int a = 1; a < 16; ++a) if (v[a] > m0) { m0 = v[a]; i0 = a; }
        v[i0] = -INFINITY;
        int i1 = 0; float m1 = v[0];
        #pragma unroll
        for (int a = 1; a < 16; ++a) if (v[a] > m1) { m1 = v[a]; i1 = a; }
        v[i1] = -INFINITY;
        int i2 = 0; float m2 = v[0];
        #pragma unroll
        for (int a = 1; a < 16; ++a) if (v[a] > m2) { m2 = v[a]; i2 = a; }
        float e1 = expf(m1 - m0), e2 = expf(m2 - m0);
        float s = 1.0f + e1 + e2;
        float4 r;
        r.x = 1.0f / s;
        r.y = e1 / s;
        r.z = e2 / s;
        r.w = (float)(i0 | (i1 << 4) | (i2 << 8));
        selout[(size_t)b * NT + t0 + jt] = r;
    }
}

// ---------- K5: placement * smoothed upsampled envelope (piecewise-constant) ----------
__global__ __launch_bounds__(256)
void k_out(const float* __restrict__ env,
           const float4* __restrict__ sel,
           const float* __restrict__ atoms,
           const float* __restrict__ smw,
           float* __restrict__ out)
{
    __shared__ float at[512];
    __shared__ float ps[8];
    const int tid = threadIdx.x;
    for (int i = tid; i < 512; i += 256) at[i] = atoms[i];
    if (tid == 0) {
        float s = 0.0f;
        #pragma unroll
        for (int c = 0; c < 7; ++c) { ps[c] = s; s += smw[c]; }
        ps[7] = s;
    }
    __syncthreads();

    const int fid  = blockIdx.x * 4 + (tid >> 6);
    const int b    = fid >> 12;
    const int t    = fid & 4095;
    const int lane = tid & 63;
    const int base = b * LTOT + t * 240;

    if (lane < 8) {
        const float4 sv = sel[fid];
        const int p  = (int)(sv.w + 0.5f);
        const int i0 = p & 15, i1 = (p >> 4) & 15, i2 = (p >> 8) & 15;
        const int j0 = lane * 4;
        float r[4];
        if (t == 0 || t == NT - 1) {
            #pragma unroll
            for (int q = 0; q < 4; ++q) {
                const int j = j0 + q;
                const float fv = sv.x * at[i0 * 32 + j] + sv.y * at[i1 * 32 + j] + sv.z * at[i2 * 32 + j];
                const int ip = t * 240 + j;
                float es = 0.0f;
                #pragma unroll
                for (int d = -3; d <= 3; ++d) {
                    const int ii = ip + d;
                    if (ii >= 0 && ii < LTOT) {
                        const int nn = (int)((double)ii * (4096.0 / 982832.0));
                        es = fmaf(smw[d + 3], env[b * NT + nn], es);
                    }
                }
                r[q] = fv * es;
            }
        } else {
            const int ip0 = t * 240;
            const int ii0 = ip0 - 3;
            const int n0  = (int)((double)ii0 * (4096.0 / 982832.0));
            int K = ((n0 + 1) * 61427 + 255) >> 8;
            if ((int)((double)(K - 1) * (4096.0 / 982832.0)) > n0) --K;
            else if ((int)((double)K * (4096.0 / 982832.0)) == n0) ++K;
            const float e0 = env[b * NT + n0];
            const int   n1 = (n0 + 1 < NT) ? n0 + 1 : NT - 1;
            const float e1 = env[b * NT + n1];
            const float pst = ps[7];
            #pragma unroll
            for (int q = 0; q < 4; ++q) {
                const int j = j0 + q;
                const int ip = ip0 + j;
                int c = K - (ip - 3);
                c = (c < 0) ? 0 : ((c > 7) ? 7 : c);
                const float A  = ps[c];
                const float es = fmaf(A, e0 - e1, pst * e1);
                const float fv = sv.x * at[i0 * 32 + j] + sv.y * at[i1 * 32 + j] + sv.z * at[i2 * 32 + j];
                r[q] = fv * es;
            }
        }
        *(float4*)(out + base + j0) = make_float4(r[0], r[1], r[2], r[3]);
    } else if (lane < 60) {
        const int idx = t * 240 + lane * 4;
        if (idx + 4 <= LTOT) {
            *(float4*)(out + base + lane * 4) = make_float4(0.0f, 0.0f, 0.0f, 0.0f);
        }
    }
}

extern "C" void kernel_launch(void* const* d_in, const int* in_sizes, int n_in,
                              void* d_out, int out_size, void* d_ws, size_t ws_size,
                              hipStream_t stream)
{
    const float* cond  = (const float*)d_in[0];
    const float* dw1w  = (const float*)d_in[2];
    const float* dw1b  = (const float*)d_in[3];
    const float* pw1w  = (const float*)d_in[4];
    const float* pw1b  = (const float*)d_in[5];
    const float* dw2w  = (const float*)d_in[6];
    const float* dw2b  = (const float*)d_in[7];
    const float* pw2w  = (const float*)d_in[8];
    const float* pw2b  = (const float*)d_in[9];
    const float* envw  = (const float*)d_in[10];
    const float* envb  = (const float*)d_in[11];
    const float* smw   = (const float*)d_in[12];
    const float* sdww  = (const float*)d_in[13];
    const float* sdwb  = (const float*)d_in[14];
    const float* spww  = (const float*)d_in[15];
    const float* spwb  = (const float*)d_in[16];
    const float* selw  = (const float*)d_in[17];
    const float* selb  = (const float*)d_in[18];
    const float* atoms = (const float*)d_in[19];
    float* out = (float*)d_out;

    // ws: env 512KB | selbuf 2MB | y1/ss shared 33.55MB | weff1 96KB | weff2 96KB | beff 512B
    const size_t SZ_ENV = 524288;
    const size_t SZ_SEL = 2097152;
    const size_t SZ_Y1  = 33554432;

    float*  envbuf = (float*)d_ws;
    float4* selbuf = (float4*)((char*)d_ws + SZ_ENV);
    float*  y1buf  = (float*)((char*)d_ws + SZ_ENV + SZ_SEL);
    float*  weff1  = (float*)((char*)d_ws + SZ_ENV + SZ_SEL + SZ_Y1);
    float*  weff2  = weff1 + 24576;
    float*  beff1  = weff2 + 24576;
    float*  beff2  = beff1 + 64;

    k_wt2<<<97, 256, 0, stream>>>(pw1w, dw1w, dw1b, pw1b, spww, sdww, sdwb, spwb,
                                  weff1, beff1, weff2, beff2);

    dim3 g(NT / BT, NB);                     // 64 x 32
    const int gr = (NB * NT) / 128;          // 1024 blocks (128 cols each)
    k_stage1w<<<gr, 256, 0, stream>>>(cond, weff1, beff1, y1buf);
    k_env2<<<g, 256, 0, stream>>>(y1buf, dw2w, dw2b, pw2w, pw2b, envw, envb, envbuf);
    k_stage1w<<<gr, 256, 0, stream>>>(cond, weff2, beff2, y1buf);
    k_sel2<<<g, 256, 0, stream>>>(y1buf, selw, selb, selbuf);
    k_out<<<(NB * NT) / 4, 256, 0, stream>>>(envbuf, selbuf, atoms, smw, out);
}

// Round 14
// 192.306 us; speedup vs baseline: 2.1971x; 2.1971x over previous
//
#include <hip/hip_runtime.h>
#include <math.h>

#define NB 32
#define NC 128
#define NT 4096
#define LTOT 982832   // (4096-1)*240 + 32
#define BT 64

__device__ __forceinline__ float lrelu_(float x) { return x > 0.0f ? x : 0.1f * x; }
// channel-granule XOR swizzle (row-strided b128 reads conflict-free) — env2/sel2 tiles
__device__ __forceinline__ int swz_(int row, int ch) {
    return ((ch & ~3) ^ ((row & 56) >> 1)) | (ch & 3);
}

// ---------- K0: transpose pointwise weights [64][128] -> [128][64] (both paths) ----------
__global__ __launch_bounds__(256)
void k_wt(const float* __restrict__ pw1w, const float* __restrict__ spww,
          float* __restrict__ wt1, float* __restrict__ wt2)
{
    const int i = blockIdx.x * 256 + threadIdx.x;   // 8192 elements
    if (i < 64 * 128) {
        const int o = i >> 7, c = i & 127;
        wt1[c * 64 + o] = pw1w[i];
        wt2[c * 64 + o] = spww[i];
    }
}

// ---------- K1/K3: depthwise k3 + pointwise 128->64 + lrelu -> [b][t][64] ----------
// R11 skeleton (acc[32], wave-uniform o-half, SGPR weights, zero LDS/barriers),
// c-loop in explicit 8-channel batches: 24 loads issued together, then 8x35 FMA
// (~560 cy/wave) -> 3 sibling waves give ~1680 cy latency cover per batch.
__global__ __launch_bounds__(256, 4)
void k_stage1r(const float* __restrict__ cond,
               const float* __restrict__ dww, const float* __restrict__ dwb,
               const float* __restrict__ wt,  const float* __restrict__ pwb,
               float* __restrict__ out64)
{
    const int tid  = threadIdx.x;
    const int lane = tid & 63;
    const int wv   = tid >> 6;                      // 0..3
    const int cgrp = wv >> 1;                       // 0..1 : col group
    const int so0  = __builtin_amdgcn_readfirstlane((wv & 1) * 32);  // o-half base

    const int col = blockIdx.x * 128 + cgrp * 64 + lane;   // global column b*NT+t
    const int b   = col >> 12;
    const int t   = col & (NT - 1);
    const float* xp0 = cond + (size_t)b * NC * NT + t;
    const bool gm = (t >= 1);
    const bool gp = (t + 1 < NT);

    float acc[32];
    #pragma unroll
    for (int o = 0; o < 32; ++o) acc[o] = 0.0f;

    #pragma unroll 1
    for (int cc = 0; cc < NC; cc += 8) {
        float xm[8], xc[8], xq[8];
        #pragma unroll
        for (int u = 0; u < 8; ++u) {
            const float* row = xp0 + (size_t)(cc + u) * NT;
            xm[u] = gm ? row[-1] : 0.0f;
            xc[u] = row[0];
            xq[u] = gp ? row[1] : 0.0f;
        }
        #pragma unroll
        for (int u = 0; u < 8; ++u) {
            const int c = cc + u;
            const float h = fmaf(dww[c * 3 + 0], xm[u],
                            fmaf(dww[c * 3 + 1], xc[u],
                            fmaf(dww[c * 3 + 2], xq[u], dwb[c])));
            const float* wr = wt + (c << 6) + so0;   // wave-uniform -> s_load
            #pragma unroll
            for (int og = 0; og < 4; ++og) {
                const float4 wa = *(const float4*)(wr + og * 8);
                const float4 wb = *(const float4*)(wr + og * 8 + 4);
                acc[og * 8 + 0] = fmaf(wa.x, h, acc[og * 8 + 0]);
                acc[og * 8 + 1] = fmaf(wa.y, h, acc[og * 8 + 1]);
                acc[og * 8 + 2] = fmaf(wa.z, h, acc[og * 8 + 2]);
                acc[og * 8 + 3] = fmaf(wa.w, h, acc[og * 8 + 3]);
                acc[og * 8 + 4] = fmaf(wb.x, h, acc[og * 8 + 4]);
                acc[og * 8 + 5] = fmaf(wb.y, h, acc[og * 8 + 5]);
                acc[og * 8 + 6] = fmaf(wb.z, h, acc[og * 8 + 6]);
                acc[og * 8 + 7] = fmaf(wb.w, h, acc[og * 8 + 7]);
            }
        }
    }

    float* op = out64 + (size_t)col * 64 + so0;
    #pragma unroll
    for (int g = 0; g < 8; ++g) {
        const float4 bb = *(const float4*)&pwb[so0 + g * 4];
        float4 r;
        r.x = lrelu_(acc[g * 4 + 0] + bb.x);
        r.y = lrelu_(acc[g * 4 + 1] + bb.y);
        r.z = lrelu_(acc[g * 4 + 2] + bb.z);
        r.w = lrelu_(acc[g * 4 + 3] + bb.w);
        *(float4*)(op + g * 4) = r;
    }
}

// ---------- K2: dw2(k3,64ch) -> pw2(64->32)+lrelu -> env(k3,32->1) -> sigmoid ----------
__global__ __launch_bounds__(256)
void k_env2(const float* __restrict__ y1,   // [b][t][64]
            const float* __restrict__ dw2w, const float* __restrict__ dw2b,
            const float* __restrict__ pw2w, const float* __restrict__ pw2b,
            const float* __restrict__ envw, const float* __restrict__ envb,
            float* __restrict__ envout)
{
    __shared__ float Y1T[70 * 68];
    __shared__ float H2T[68 * 68];
    float* Y2T = Y1T;

    const int tid = threadIdx.x;
    const int b   = blockIdx.y;
    const int t0  = blockIdx.x * BT;

    for (int i = tid; i < 70 * 64; i += 256) {
        int j = i >> 6, o = i & 63;
        int t = t0 - 3 + j;
        Y1T[j * 68 + o] = (t >= 0 && t < NT) ? y1[((size_t)b * NT + t) * 64 + o] : 0.0f;
    }
    __syncthreads();

    {
        const int o = tid & 63;
        const int g = tid >> 6;
        const float d0 = dw2w[o * 3 + 0], d1 = dw2w[o * 3 + 1], d2 = dw2w[o * 3 + 2], db = dw2b[o];
        float y[19];
        #pragma unroll
        for (int k = 0; k < 19; ++k) y[k] = Y1T[(g * 17 + k) * 68 + o];
        #pragma unroll
        for (int i = 0; i < 17; ++i) {
            int jj = g * 17 + i;
            H2T[jj * 68 + swz_(jj, o)] = fmaf(d0, y[i], fmaf(d1, y[i + 1], fmaf(d2, y[i + 2], db)));
        }
    }
    __syncthreads();

    {
        const int v  = tid & 63;
        const int wu = __builtin_amdgcn_readfirstlane(threadIdx.x >> 6);
        const float* wbase = pw2w + wu * 8 * 64;
        float acc[8], acc2[8];
        #pragma unroll
        for (int q = 0; q < 8; ++q) { acc[q] = 0.0f; acc2[q] = 0.0f; }
        const int r1 = v + 1;
        const int r2 = (v < 2) ? v + 65 : v + 1;
        const float* h1 = &H2T[r1 * 68]; const int x1 = (r1 & 56) >> 1;
        const float* h2 = &H2T[r2 * 68]; const int x2 = (r2 & 56) >> 1;
        #pragma unroll 2
        for (int cc = 0; cc < 64; cc += 4) {
            const float4 a  = *(const float4*)&h1[cc ^ x1];
            const float4 c2 = *(const float4*)&h2[cc ^ x2];
            #pragma unroll
            for (int q = 0; q < 8; ++q) {
                const float4 wv = *(const float4*)&wbase[q * 64 + cc];
                acc[q]  = fmaf(wv.x, a.x,  fmaf(wv.y, a.y,  fmaf(wv.z, a.z,  fmaf(wv.w, a.w,  acc[q]))));
                acc2[q] = fmaf(wv.x, c2.x, fmaf(wv.y, c2.y, fmaf(wv.z, c2.z, fmaf(wv.w, c2.w, acc2[q]))));
            }
        }
        const int t1 = t0 - 1 + v;
        const bool ok1 = (t1 >= 0 && t1 < NT);
        #pragma unroll
        for (int q = 0; q < 8; ++q) {
            const float bq = pw2b[wu * 8 + q];
            Y2T[v * 37 + wu * 8 + q] = ok1 ? lrelu_(acc[q] + bq) : 0.0f;
        }
        if (v < 2) {
            const int ve = v + 64;
            const int t2 = t0 - 1 + ve;
            const bool ok2 = (t2 >= 0 && t2 < NT);
            #pragma unroll
            for (int q = 0; q < 8; ++q) {
                const float bq = pw2b[wu * 8 + q];
                Y2T[ve * 37 + wu * 8 + q] = ok2 ? lrelu_(acc2[q] + bq) : 0.0f;
            }
        }
    }
    __syncthreads();

    {
        const int j  = tid >> 2;
        const int cp = tid & 3;
        float a = 0.0f;
        #pragma unroll
        for (int d = 0; d < 3; ++d) {
            const float* yr = &Y2T[(j + d) * 37 + cp * 8];
            #pragma unroll
            for (int k = 0; k < 8; ++k)
                a = fmaf(envw[(cp * 8 + k) * 3 + d], yr[k], a);
        }
        a += __shfl_xor(a, 1);
        a += __shfl_xor(a, 2);
        if (cp == 0) {
            const float z = a + envb[0];
            envout[(size_t)b * NT + t0 + j] = 1.0f / (1.0f + expf(-z));
        }
    }
}

// ---------- K4: sel conv (64->16, k3) -> top3 -> softmax ----------
__global__ __launch_bounds__(256)
void k_sel2(const float* __restrict__ ss,   // [b][t][64]
            const float* __restrict__ selw, const float* __restrict__ selb,
            float4* __restrict__ selout)
{
    __shared__ float SST[66 * 68];
    __shared__ float Lg[16 * 64];

    const int tid = threadIdx.x;
    const int b   = blockIdx.y;
    const int t0  = blockIdx.x * BT;

    for (int i = tid; i < 66 * 64; i += 256) {
        int j = i >> 6, o = i & 63;
        int t = t0 - 1 + j;
        SST[j * 68 + swz_(j, o)] = (t >= 0 && t < NT) ? ss[((size_t)b * NT + t) * 64 + o] : 0.0f;
    }
    __syncthreads();

    {
        const int v  = tid & 63;
        const int wu = __builtin_amdgcn_readfirstlane(threadIdx.x >> 6);
        float acc[4] = {0.0f, 0.0f, 0.0f, 0.0f};
        const float* r0 = &SST[(v + 0) * 68]; const int x0 = ((v + 0) & 56) >> 1;
        const float* r1 = &SST[(v + 1) * 68]; const int x1 = ((v + 1) & 56) >> 1;
        const float* r2 = &SST[(v + 2) * 68]; const int x2 = ((v + 2) & 56) >> 1;
        #pragma unroll 2
        for (int cc = 0; cc < 64; cc += 4) {
            const float4 s0 = *(const float4*)&r0[cc ^ x0];
            const float4 s1 = *(const float4*)&r1[cc ^ x1];
            const float4 s2 = *(const float4*)&r2[cc ^ x2];
            #pragma unroll
            for (int q = 0; q < 4; ++q) {
                const float* wr = selw + (size_t)(wu * 4 + q) * 192 + cc * 3;
                const float4 wA = *(const float4*)&wr[0];
                const float4 wB = *(const float4*)&wr[4];
                const float4 wC = *(const float4*)&wr[8];
                acc[q] = fmaf(wA.x, s0.x, acc[q]); acc[q] = fmaf(wA.y, s1.x, acc[q]); acc[q] = fmaf(wA.z, s2.x, acc[q]);
                acc[q] = fmaf(wA.w, s0.y, acc[q]); acc[q] = fmaf(wB.x, s1.y, acc[q]); acc[q] = fmaf(wB.y, s2.y, acc[q]);
                acc[q] = fmaf(wB.z, s0.z, acc[q]); acc[q] = fmaf(wB.w, s1.z, acc[q]); acc[q] = fmaf(wC.x, s2.z, acc[q]);
                acc[q] = fmaf(wC.y, s0.w, acc[q]); acc[q] = fmaf(wC.z, s1.w, acc[q]); acc[q] = fmaf(wC.w, s2.w, acc[q]);
            }
        }
        #pragma unroll
        for (int q = 0; q < 4; ++q)
            Lg[(wu * 4 + q) * 64 + v] = acc[q] + selb[wu * 4 + q];
    }
    __syncthreads();

    if (tid < 64) {
        const int jt = tid;
        float v[16];
        #pragma unroll
        for (int a = 0; a < 16; ++a) v[a] = Lg[a * 64 + jt];
        int i0 = 0; float m0 = v[0];
        #pragma unroll
        for (int a = 1; a < 16; ++a) if (v[a] > m0) { m0 = v[a]; i0 = a; }
        v[i0] = -INFINITY;
        int i1 = 0; float m1 = v[0];
        #pragma unroll
        for (int a = 1; a < 16; ++a) if (v[a] > m1) { m1 = v[a]; i1 = a; }
        v[i1] = -INFINITY;
        int i2 = 0; float m2 = v[0];
        #pragma unroll
        for (int a = 1; a < 16; ++a) if (v[a] > m2) { m2 = v[a]; i2 = a; }
        float e1 = expf(m1 - m0), e2 = expf(m2 - m0);
        float s = 1.0f + e1 + e2;
        float4 r;
        r.x = 1.0f / s;
        r.y = e1 / s;
        r.z = e2 / s;
        r.w = (float)(i0 | (i1 << 4) | (i2 << 8));
        selout[(size_t)b * NT + t0 + jt] = r;
    }
}

// ---------- K5: placement * smoothed upsampled envelope (piecewise-constant) ----------
__global__ __launch_bounds__(256)
void k_out(const float* __restrict__ env,
           const float4* __restrict__ sel,
           const float* __restrict__ atoms,
           const float* __restrict__ smw,
           float* __restrict__ out)
{
    __shared__ float at[512];
    __shared__ float ps[8];
    const int tid = threadIdx.x;
    for (int i = tid; i < 512; i += 256) at[i] = atoms[i];
    if (tid == 0) {
        float s = 0.0f;
        #pragma unroll
        for (int c = 0; c < 7; ++c) { ps[c] = s; s += smw[c]; }
        ps[7] = s;
    }
    __syncthreads();

    const int fid  = blockIdx.x * 4 + (tid >> 6);
    const int b    = fid >> 12;
    const int t    = fid & 4095;
    const int lane = tid & 63;
    const int base = b * LTOT + t * 240;

    if (lane < 8) {
        const float4 sv = sel[fid];
        const int p  = (int)(sv.w + 0.5f);
        const int i0 = p & 15, i1 = (p >> 4) & 15, i2 = (p >> 8) & 15;
        const int j0 = lane * 4;
        float r[4];
        if (t == 0 || t == NT - 1) {
            #pragma unroll
            for (int q = 0; q < 4; ++q) {
                const int j = j0 + q;
                const float fv = sv.x * at[i0 * 32 + j] + sv.y * at[i1 * 32 + j] + sv.z * at[i2 * 32 + j];
                const int ip = t * 240 + j;
                float es = 0.0f;
                #pragma unroll
                for (int d = -3; d <= 3; ++d) {
                    const int ii = ip + d;
                    if (ii >= 0 && ii < LTOT) {
                        const int nn = (int)((double)ii * (4096.0 / 982832.0));
                        es = fmaf(smw[d + 3], env[b * NT + nn], es);
                    }
                }
                r[q] = fv * es;
            }
        } else {
            const int ip0 = t * 240;
            const int ii0 = ip0 - 3;
            const int n0  = (int)((double)ii0 * (4096.0 / 982832.0));
            int K = ((n0 + 1) * 61427 + 255) >> 8;
            if ((int)((double)(K - 1) * (4096.0 / 982832.0)) > n0) --K;
            else if ((int)((double)K * (4096.0 / 982832.0)) == n0) ++K;
            const float e0 = env[b * NT + n0];
            const int   n1 = (n0 + 1 < NT) ? n0 + 1 : NT - 1;
            const float e1 = env[b * NT + n1];
            const float pst = ps[7];
            #pragma unroll
            for (int q = 0; q < 4; ++q) {
                const int j = j0 + q;
                const int ip = ip0 + j;
                int c = K - (ip - 3);
                c = (c < 0) ? 0 : ((c > 7) ? 7 : c);
                const float A  = ps[c];
                const float es = fmaf(A, e0 - e1, pst * e1);
                const float fv = sv.x * at[i0 * 32 + j] + sv.y * at[i1 * 32 + j] + sv.z * at[i2 * 32 + j];
                r[q] = fv * es;
            }
        }
        *(float4*)(out + base + j0) = make_float4(r[0], r[1], r[2], r[3]);
    } else if (lane < 60) {
        const int idx = t * 240 + lane * 4;
        if (idx + 4 <= LTOT) {
            *(float4*)(out + base + lane * 4) = make_float4(0.0f, 0.0f, 0.0f, 0.0f);
        }
    }
}

extern "C" void kernel_launch(void* const* d_in, const int* in_sizes, int n_in,
                              void* d_out, int out_size, void* d_ws, size_t ws_size,
                              hipStream_t stream)
{
    const float* cond  = (const float*)d_in[0];
    const float* dw1w  = (const float*)d_in[2];
    const float* dw1b  = (const float*)d_in[3];
    const float* pw1w  = (const float*)d_in[4];
    const float* pw1b  = (const float*)d_in[5];
    const float* dw2w  = (const float*)d_in[6];
    const float* dw2b  = (const float*)d_in[7];
    const float* pw2w  = (const float*)d_in[8];
    const float* pw2b  = (const float*)d_in[9];
    const float* envw  = (const float*)d_in[10];
    const float* envb  = (const float*)d_in[11];
    const float* smw   = (const float*)d_in[12];
    const float* sdww  = (const float*)d_in[13];
    const float* sdwb  = (const float*)d_in[14];
    const float* spww  = (const float*)d_in[15];
    const float* spwb  = (const float*)d_in[16];
    const float* selw  = (const float*)d_in[17];
    const float* selb  = (const float*)d_in[18];
    const float* atoms = (const float*)d_in[19];
    float* out = (float*)d_out;

    // ws: env 512KB | selbuf 2MB | y1/ss shared 33.55MB | wt1 32KB | wt2 32KB
    const size_t SZ_ENV = 524288;
    const size_t SZ_SEL = 2097152;
    const size_t SZ_Y1  = 33554432;

    float*  envbuf = (float*)d_ws;
    float4* selbuf = (float4*)((char*)d_ws + SZ_ENV);
    float*  y1buf  = (float*)((char*)d_ws + SZ_ENV + SZ_SEL);
    float*  wt1    = (float*)((char*)d_ws + SZ_ENV + SZ_SEL + SZ_Y1);
    float*  wt2    = wt1 + 64 * 128;

    k_wt<<<32, 256, 0, stream>>>(pw1w, spww, wt1, wt2);

    dim3 g(NT / BT, NB);                     // 64 x 32
    const int gr = (NB * NT) / 128;          // 1024 blocks (128 cols each)
    k_stage1r<<<gr, 256, 0, stream>>>(cond, dw1w, dw1b, wt1, pw1b, y1buf);
    k_env2<<<g, 256, 0, stream>>>(y1buf, dw2w, dw2b, pw2w, pw2b, envw, envb, envbuf);
    k_stage1r<<<gr, 256, 0, stream>>>(cond, sdww, sdwb, wt2, spwb, y1buf);
    k_sel2<<<g, 256, 0, stream>>>(y1buf, selw, selb, selbuf);
    k_out<<<(NB * NT) / 4, 256, 0, stream>>>(envbuf, selbuf, atoms, smw, out);
}